// Round 1
// baseline (783.084 us; speedup 1.0000x reference)
//
#include <hip/hip_runtime.h>
#include <hip/hip_bf16.h>

#define D_FEAT 64

// Kernel A: out = features  (the "+ I @ features" self-loop term), vectorized.
__global__ void gp_init_kernel(const float4* __restrict__ feat,
                               float4* __restrict__ out, int n4) {
    int i = blockIdx.x * blockDim.x + threadIdx.x;
    int stride = gridDim.x * blockDim.x;
    for (; i < n4; i += stride) {
        out[i] = feat[i];
    }
}

// Kernel B: one 64-lane wave per edge; lane = feature index.
// Coalesced 256B gather of features[cols[e]], coalesced atomic scatter-add
// into out[rows[e]].
__global__ void gp_edge_kernel(const float* __restrict__ feat,
                               const float* __restrict__ vals,
                               const int* __restrict__ rows,
                               const int* __restrict__ cols,
                               float* __restrict__ out, int n_edges) {
    int lane = threadIdx.x & 63;
    long long gtid = (long long)blockIdx.x * blockDim.x + threadIdx.x;
    int e = (int)(gtid >> 6);
    if (e >= n_edges) return;

    int r = rows[e];
    int c = cols[e];
    float v = vals[e];
    float x = feat[(long long)c * D_FEAT + lane];
    // Native global_atomic_add_f32 (plain atomicAdd would be a CAS loop
    // without -munsafe-fp-atomics).
    unsafeAtomicAdd(&out[(long long)r * D_FEAT + lane], v * x);
}

extern "C" void kernel_launch(void* const* d_in, const int* in_sizes, int n_in,
                              void* d_out, int out_size, void* d_ws, size_t ws_size,
                              hipStream_t stream) {
    const float* feat = (const float*)d_in[0];   // [N, 64]
    const float* vals = (const float*)d_in[1];   // [E]
    const int*   rows = (const int*)d_in[2];     // [E]
    const int*   cols = (const int*)d_in[3];     // [E]
    float* out = (float*)d_out;                  // [N, 64]

    int n_edges = in_sizes[1];
    int n_elems = out_size;          // N * 64
    int n4 = n_elems / 4;

    // out = features
    {
        int block = 256;
        int grid = (n4 + block - 1) / block;
        if (grid > 4096) grid = 4096;
        gp_init_kernel<<<grid, block, 0, stream>>>(
            (const float4*)feat, (float4*)out, n4);
    }

    // scatter-add edges
    {
        int block = 256;                       // 4 waves = 4 edges per block
        long long total_threads = (long long)n_edges * 64;
        int grid = (int)((total_threads + block - 1) / block);
        gp_edge_kernel<<<grid, block, 0, stream>>>(
            feat, vals, rows, cols, out, n_edges);
    }
}

// Round 2
// 642.331 us; speedup vs baseline: 1.2191x; 1.2191x over previous
//
#include <hip/hip_runtime.h>
#include <hip/hip_bf16.h>

#define D 64

// ---------- CSR build ----------

// K1: histogram of destination rows (int atomics, 3.2M vs 204.8M float before)
__global__ void k_hist(const int* __restrict__ rows, int* __restrict__ counts, int E) {
    int i = blockIdx.x * blockDim.x + threadIdx.x;
    int stride = gridDim.x * blockDim.x;
    for (; i < E; i += stride) atomicAdd(&counts[rows[i]], 1);
}

// S1: per-block (1024-elem) exclusive scan of counts -> offsets; block totals -> blocksums
__global__ void k_scan1(const int* __restrict__ counts, int* __restrict__ offsets,
                        int* __restrict__ blocksums, int N) {
    __shared__ int lds[256];
    int t = threadIdx.x;
    int base = blockIdx.x * 1024 + t * 4;
    int v[4];
#pragma unroll
    for (int k = 0; k < 4; ++k) v[k] = (base + k < N) ? counts[base + k] : 0;
    int s = v[0] + v[1] + v[2] + v[3];
    lds[t] = s;
    __syncthreads();
    for (int off = 1; off < 256; off <<= 1) {
        int x = (t >= off) ? lds[t - off] : 0;
        __syncthreads();
        lds[t] += x;
        __syncthreads();
    }
    int excl = lds[t] - s;
    if (t == 255) blocksums[blockIdx.x] = lds[255];
    int run = excl;
#pragma unroll
    for (int k = 0; k < 4; ++k) {
        if (base + k < N) offsets[base + k] = run;
        run += v[k];
    }
}

// S2: single-block exclusive scan of blocksums (B <= 1024)
__global__ void k_scan2(int* __restrict__ blocksums, int B) {
    __shared__ int lds[1024];
    int t = threadIdx.x;
    int v = (t < B) ? blocksums[t] : 0;
    lds[t] = v;
    __syncthreads();
    for (int off = 1; off < 1024; off <<= 1) {
        int x = (t >= off) ? lds[t - off] : 0;
        __syncthreads();
        lds[t] += x;
        __syncthreads();
    }
    if (t < B) blocksums[t] = lds[t] - v;  // exclusive
}

// S3: add scanned block offset to each element
__global__ void k_scan3(int* __restrict__ offsets, const int* __restrict__ blocksums, int N) {
    int add = blocksums[blockIdx.x];
    int base = blockIdx.x * 1024 + threadIdx.x * 4;
#pragma unroll
    for (int k = 0; k < 4; ++k)
        if (base + k < N) offsets[base + k] += add;
}

// K3: scatter edges into CSR slots. offsets[] mutates into "end" positions.
// packed = {hi: bits of val, lo: col}
__global__ void k_scatter(const int* __restrict__ rows, const int* __restrict__ cols,
                          const float* __restrict__ vals, int* __restrict__ offsets,
                          unsigned long long* __restrict__ packed, int E) {
    int i = blockIdx.x * blockDim.x + threadIdx.x;
    int stride = gridDim.x * blockDim.x;
    for (; i < E; i += stride) {
        int r = rows[i];
        int pos = atomicAdd(&offsets[r], 1);
        unsigned long long d =
            ((unsigned long long)__float_as_uint(vals[i]) << 32) | (unsigned)cols[i];
        packed[pos] = d;
    }
}

// K4: one wave per output row. lane = feature index. Register accumulation,
// single non-atomic store, self-loop fused. Edge descriptors loaded 64-at-a-time
// coalesced, then broadcast via shfl (register-only inner loop except gather).
__global__ void __launch_bounds__(256) k_spmm(const float* __restrict__ feat,
                                              const unsigned long long* __restrict__ packed,
                                              const int* __restrict__ offsets_end,
                                              const int* __restrict__ counts,
                                              float* __restrict__ out, int N) {
    int lane = threadIdx.x & 63;
    int wid = (int)(((long long)blockIdx.x * blockDim.x + threadIdx.x) >> 6);
    if (wid >= N) return;
    int end = offsets_end[wid];
    int cnt = counts[wid];
    int start = end - cnt;

    float acc = feat[(size_t)wid * D + lane];  // + I @ features
    for (int base = start; base < end; base += 64) {
        int m = end - base;
        if (m > 64) m = 64;
        unsigned long long d = (base + lane < end) ? packed[base + lane] : 0ULL;
        for (int j = 0; j < m; ++j) {
            unsigned long long dj = __shfl(d, j, 64);
            int c = (int)(unsigned)(dj & 0xffffffffULL);
            float v = __uint_as_float((unsigned)(dj >> 32));
            acc = fmaf(v, feat[(size_t)c * D + lane], acc);
        }
    }
    out[(size_t)wid * D + lane] = acc;
}

// ---------- fallback (round-1 atomic path) ----------
__global__ void gp_init_kernel(const float4* __restrict__ feat, float4* __restrict__ out,
                               int n4) {
    int i = blockIdx.x * blockDim.x + threadIdx.x;
    int stride = gridDim.x * blockDim.x;
    for (; i < n4; i += stride) out[i] = feat[i];
}
__global__ void gp_edge_kernel(const float* __restrict__ feat, const float* __restrict__ vals,
                               const int* __restrict__ rows, const int* __restrict__ cols,
                               float* __restrict__ out, int n_edges) {
    int lane = threadIdx.x & 63;
    long long gtid = (long long)blockIdx.x * blockDim.x + threadIdx.x;
    int e = (int)(gtid >> 6);
    if (e >= n_edges) return;
    int r = rows[e];
    int c = cols[e];
    float v = vals[e];
    float x = feat[(long long)c * D + lane];
    unsafeAtomicAdd(&out[(long long)r * D + lane], v * x);
}

extern "C" void kernel_launch(void* const* d_in, const int* in_sizes, int n_in,
                              void* d_out, int out_size, void* d_ws, size_t ws_size,
                              hipStream_t stream) {
    const float* feat = (const float*)d_in[0];  // [N, 64]
    const float* vals = (const float*)d_in[1];  // [E]
    const int* rows = (const int*)d_in[2];      // [E]
    const int* cols = (const int*)d_in[3];      // [E]
    float* out = (float*)d_out;                 // [N, 64]

    int E = in_sizes[1];
    int N = out_size / D;
    int B = (N + 1023) / 1024;

    size_t off_counts = (size_t)E * 8;                 // packed edges first
    size_t off_offsets = off_counts + (size_t)N * 4;
    size_t off_blocksums = off_offsets + (size_t)N * 4;
    size_t needed = off_blocksums + 1024 * 4;

    if (ws_size >= needed && B <= 1024) {
        char* ws = (char*)d_ws;
        unsigned long long* packed = (unsigned long long*)ws;
        int* counts = (int*)(ws + off_counts);
        int* offsets = (int*)(ws + off_offsets);
        int* blocksums = (int*)(ws + off_blocksums);

        hipMemsetAsync(counts, 0, (size_t)N * 4, stream);

        int gE = (E + 255) / 256;
        if (gE > 4096) gE = 4096;
        k_hist<<<gE, 256, 0, stream>>>(rows, counts, E);
        k_scan1<<<B, 256, 0, stream>>>(counts, offsets, blocksums, N);
        k_scan2<<<1, 1024, 0, stream>>>(blocksums, B);
        k_scan3<<<B, 256, 0, stream>>>(offsets, blocksums, N);
        k_scatter<<<gE, 256, 0, stream>>>(rows, cols, vals, offsets, packed, E);

        long long tt = (long long)N * 64;
        k_spmm<<<(int)((tt + 255) / 256), 256, 0, stream>>>(feat, packed, offsets, counts, out, N);
    } else {
        // fallback: atomic scatter (round-1)
        int n4 = out_size / 4;
        int grid = (n4 + 255) / 256;
        if (grid > 4096) grid = 4096;
        gp_init_kernel<<<grid, 256, 0, stream>>>((const float4*)feat, (float4*)out, n4);
        long long tthreads = (long long)E * 64;
        gp_edge_kernel<<<(int)((tthreads + 255) / 256), 256, 0, stream>>>(feat, vals, rows, cols,
                                                                          out, E);
    }
}